// Round 14
// baseline (360.251 us; speedup 1.0000x reference)
//
#include <hip/hip_runtime.h>
#include <hip/hip_bf16.h>

typedef _Float16 f16x8 __attribute__((ext_vector_type(8)));
typedef _Float16 f16x2 __attribute__((ext_vector_type(2)));
typedef float f32x4  __attribute__((ext_vector_type(4)));

#define Bn 4
#define Cn 64
#define Hn 128
#define Wn 128
#define HWn 16384

#define XT_BYTES    (Bn*HWn*Cn*2)
#define PKDEF_BYTES (18*4*64*8*2)
#define PKOFF_BYTES (18*3*64*8*2)
#define DUMP_OFF    (9*1024*1024)

static __device__ __forceinline__ unsigned pk_f16(float lo, float hi) {
  union { _Float16 h[2]; unsigned u; } cv;
  cv.h[0] = (_Float16)lo; cv.h[1] = (_Float16)hi;
  return cv.u;
}

// ---- merged: blocks 0..1023 transpose x -> xt; blocks 1024..1055 pack weights.
__global__ __launch_bounds__(256) void prep_all(const float* __restrict__ x,
                                                const float* __restrict__ w_off,
                                                const float* __restrict__ w_def,
                                                ushort* __restrict__ xt,
                                                ushort* __restrict__ pk_def,
                                                ushort* __restrict__ pk_off) {
  __shared__ float tile[64][68];
  const int t = threadIdx.x;
  const int blk = blockIdx.x;
  if (blk < 1024) {
    const int b = blk >> 8;
    const int pix0 = (blk & 255) * 64;
    const int y = pix0 >> 7, x0 = pix0 & 127;
    const float* xb = x + (b * Cn) * HWn + pix0;
#pragma unroll
    for (int q = 0; q < 4; ++q) {
      int idx = q * 256 + t;
      int c = idx >> 4, p4 = idx & 15;
      float4 v = *(const float4*)(xb + c * HWn + p4 * 4);
      *(float4*)&tile[c][p4 * 4] = v;
    }
    __syncthreads();
    const int p = t & 63, cg = t >> 6;
#pragma unroll
    for (int half = 0; half < 2; ++half) {
      const int seg = cg * 2 + half;
      unsigned u[4];
#pragma unroll
      for (int j = 0; j < 4; ++j)
        u[j] = pk_f16(tile[seg * 8 + 2 * j][p], tile[seg * 8 + 2 * j + 1][p]);
      uint4 v = {u[0], u[1], u[2], u[3]};
      *(uint4*)(xt + (((((b << 7) + y) << 3) + seg) * 128 + x0 + p) * 8) = v;
    }
  } else {
    const int tt = (blk - 1024) * 256 + t;
    if (tt < 4608) {
      int lane = tt & 63, oc = (tt >> 6) & 3, s = tt >> 8;
      int g = s / 9, k = s % 9;
      int o = oc * 16 + (lane & 15);
      int cb = g * 32 + (lane >> 4) * 8;
      unsigned u[4];
#pragma unroll
      for (int j = 0; j < 4; ++j)
        u[j] = pk_f16(w_def[(o * Cn + cb + 2 * j) * 9 + k],
                      w_def[(o * Cn + cb + 2 * j + 1) * 9 + k]);
      uint4 v = {u[0], u[1], u[2], u[3]};
      *(uint4*)(pk_def + tt * 8) = v;
    } else if (tt < 8064) {
      int t2 = tt - 4608;
      int lane = t2 & 63, r = t2 >> 6;
      int oc = r % 3, s = r / 3;
      int k = s >> 1, chalf = s & 1;
      int o = oc * 16 + (lane & 15);
      int cb = chalf * 32 + (lane >> 4) * 8;
      unsigned u[4];
#pragma unroll
      for (int j = 0; j < 4; ++j) {
        float lo = (o < 36) ? w_off[(o * Cn + cb + 2 * j) * 9 + k] : 0.f;
        float hi = (o < 36) ? w_off[(o * Cn + cb + 2 * j + 1) * 9 + k] : 0.f;
        u[j] = pk_f16(lo, hi);
      }
      uint4 v = {u[0], u[1], u[2], u[3]};
      *(uint4*)(pk_off + (r * 64 + lane) * 8) = v;
    }
  }
}

// x-halo reverted to +/-4 (rows of 25): margin-4 vs sigma~1.2 px offsets cuts
// the wave-level global-fallback rate from ~50% of wave-taps to a few %.
#define T_STRIDE (17*25*8 + 16)

// ================= REAL fused kernel (R13 + x-halo +/-4) =================
__global__ __launch_bounds__(1024, 4) void deform_fused(const ushort* __restrict__ xt,
                                                        const ushort* __restrict__ pk_def,
                                                        const ushort* __restrict__ pk_off,
                                                        float* __restrict__ out) {
  __shared__ ushort tile[8 * T_STRIDE];      // 54,656 B
  __shared__ _Float16 off_lds[8][36][18];    // 10,368 B  (total 65,024 <= 64KB cap)
  const int t = threadIdx.x;
  const int lane = t & 63;
  const int wid = t >> 6;
  const int pg = wid >> 1, gsel = wid & 1;
  int bid = blockIdx.x;
  bid = (bid & 7) * 64 + (bid >> 3);
  const int b  = bid >> 7;
  const int ty = (bid >> 3) & 15;
  const int tx = bid & 7;
  const int y0t = ty * 8, x0t = tx * 16;
  const int TLY = max(0, y0t - 4), THY = min(127, y0t + 12);
  const int TLX = max(0, x0t - 4), THX = min(127, x0t + 20);
  const int Hd = THY - TLY + 1, Wd = THX - TLX + 1;

  {
    const int xq = t & 31;
    const int r0 = t >> 5;
    const int nr = Hd * 8;
    for (int rr = r0; rr < nr; rr += 32) {
      const int yq = rr >> 3, seg = rr & 7;
      if (xq < Wd) {
        const ushort* src = xt + ((((b << 7) + TLY + yq) << 3) + seg) * 1024 + (TLX + xq) * 8;
        *(uint4*)&tile[seg * T_STRIDE + (yq * 25 + xq) * 8] = *(const uint4*)src;
      }
    }
  }
  __syncthreads();

  const int h = y0t + pg;
  const int p = lane & 15, kq = lane >> 4;
  const int w_ = x0t + p;
  const int pixin = (h << 7) + x0t;
  const int su = gsel * 4 + kq;
  const int colb = lane & 15;

  int pixoff[9]; bool tvalid[9];
#pragma unroll
  for (int kk = 0; kk < 9; ++kk) {
    int yk = h + kk / 3 - 1, xk = w_ + kk % 3 - 1;
    tvalid[kk] = ((unsigned)yk < 128u) && ((unsigned)xk < 128u);
    int yc = min(max(yk, 0), 127), xc = min(max(xk, 0), 127);
    pixoff[kk] = ((yc - TLY) * 25 + (xc - TLX)) * 8;
  }

  { // phase 1
    f32x4 oa0 = {0,0,0,0}, oa1 = {0,0,0,0}, oa2 = {0,0,0,0};
    const f16x8* pBo = (const f16x8*)pk_off;
    f16x8 bo[2][2];
    if (gsel == 0) bo[0][0] = pBo[0*64 + lane];
    else { bo[0][0] = pBo[1*64 + lane]; bo[0][1] = pBo[2*64 + lane]; }
#pragma unroll
    for (int s = 0; s < 18; ++s) {
      if (s + 1 < 18) {
        if (gsel == 0) bo[(s + 1) & 1][0] = pBo[((s + 1)*3 + 0)*64 + lane];
        else { bo[(s + 1) & 1][0] = pBo[((s + 1)*3 + 1)*64 + lane];
               bo[(s + 1) & 1][1] = pBo[((s + 1)*3 + 2)*64 + lane]; }
      }
      const int k = s >> 1, chalf = s & 1;
      uint4 t_ = *(const uint4*)&tile[(chalf * 4 + kq) * T_STRIDE + pixoff[k]];
      if (!tvalid[k]) { t_.x = 0; t_.y = 0; t_.z = 0; t_.w = 0; }
      union { uint4 u; f16x8 v; } A; A.u = t_;
      if (gsel == 0) {
        oa0 = __builtin_amdgcn_mfma_f32_16x16x32_f16(A.v, bo[s & 1][0], oa0, 0,0,0);
      } else {
        oa1 = __builtin_amdgcn_mfma_f32_16x16x32_f16(A.v, bo[s & 1][0], oa1, 0,0,0);
        oa2 = __builtin_amdgcn_mfma_f32_16x16x32_f16(A.v, bo[s & 1][1], oa2, 0,0,0);
      }
    }
    if (gsel == 0) {
#pragma unroll
      for (int r = 0; r < 4; ++r) off_lds[pg][colb][kq * 4 + r] = (_Float16)oa0[r];
    } else {
#pragma unroll
      for (int r = 0; r < 4; ++r) {
        off_lds[pg][16 + colb][kq * 4 + r] = (_Float16)oa1[r];
        if (colb < 4) off_lds[pg][32 + colb][kq * 4 + r] = (_Float16)oa2[r];
      }
    }
  }
  __syncthreads();

  float offv[18];
#pragma unroll
  for (int j = 0; j < 18; ++j) offv[j] = (float)off_lds[pg][gsel * 18 + j][p];

  f32x4 acc0={0,0,0,0}, acc1={0,0,0,0}, acc2={0,0,0,0}, acc3={0,0,0,0};
  const f16x8* pB = (const f16x8*)pk_def;

  f16x8 bq[2][4];
  {
    const int s0 = gsel * 9;
#pragma unroll
    for (int q = 0; q < 4; ++q) bq[0][q] = pB[(s0*4 + q)*64 + lane];
  }

#pragma unroll
  for (int j = 0; j < 9; ++j) {
    if (j + 1 < 9) {
      const int s1 = gsel * 9 + j + 1;
#pragma unroll
      for (int q = 0; q < 4; ++q) bq[(j + 1) & 1][q] = pB[(s1*4 + q)*64 + lane];
    }

    const int k = j;
    float py = offv[2*j]   + (float)(h  + k / 3 - 1);
    float px = offv[2*j+1] + (float)(w_ + k % 3 - 1);
    float fy = floorf(py), fx = floorf(px);
    int y0 = (int)fy, x0 = (int)fx;
    float dy = py - fy, dx = px - fx;

    bool vy0 = (y0 >= 0) && (y0 < Hn);
    bool vy1 = (y0 >= -1) && (y0 < Hn - 1);
    bool vx0 = (x0 >= 0) && (x0 < Wn);
    bool vx1 = (x0 >= -1) && (x0 < Wn - 1);
    float omdy = 1.f - dy, omdx = 1.f - dx;
    float w00 = (vy0 && vx0) ? omdy * omdx : 0.f;
    float w01 = (vy0 && vx1) ? omdy * dx   : 0.f;
    float w10 = (vy1 && vx0) ? dy * omdx   : 0.f;
    float w11 = (vy1 && vx1) ? dy * dx     : 0.f;

    int iy0 = min(max(y0, 0), Hn - 1), iy1 = min(max(y0 + 1, 0), Hn - 1);
    int ix0 = min(max(x0, 0), Wn - 1), ix1 = min(max(x0 + 1, 0), Wn - 1);

    uint4 c00, c01, c10, c11;
    bool intile = (iy0 >= TLY) && (iy1 <= THY) && (ix0 >= TLX) && (ix1 <= THX);
    if (__all((int)intile)) {
      const int base = su * T_STRIDE;
      const int ly0 = iy0 - TLY, ly1 = iy1 - TLY;
      const int lx0 = ix0 - TLX, lx1 = ix1 - TLX;
      c00 = *(const uint4*)&tile[base + (ly0 * 25 + lx0) * 8];
      c01 = *(const uint4*)&tile[base + (ly0 * 25 + lx1) * 8];
      c10 = *(const uint4*)&tile[base + (ly1 * 25 + lx0) * 8];
      c11 = *(const uint4*)&tile[base + (ly1 * 25 + lx1) * 8];
    } else {
      const int r0g = ((((b << 7) + iy0) << 3) + su) * 128;
      const int r1g = ((((b << 7) + iy1) << 3) + su) * 128;
      c00 = *(const uint4*)(xt + (r0g + ix0) * 8);
      c01 = *(const uint4*)(xt + (r0g + ix1) * 8);
      c10 = *(const uint4*)(xt + (r1g + ix0) * 8);
      c11 = *(const uint4*)(xt + (r1g + ix1) * 8);
    }

    const _Float16 h00 = (_Float16)w00, h01 = (_Float16)w01;
    const _Float16 h10 = (_Float16)w10, h11 = (_Float16)w11;
    const f16x2 W00 = {h00, h00}, W01 = {h01, h01};
    const f16x2 W10 = {h10, h10}, W11 = {h11, h11};
    union U32H { unsigned u; f16x2 h; };
    union { uint4 u; f16x8 v; } A;
#define BILC(comp, fld)                                                        \
    { U32H a0, a1, a2, a3, r;                                                  \
      a0.u = c00.comp; a1.u = c01.comp; a2.u = c10.comp; a3.u = c11.comp;      \
      r.h = a0.h * W00 + a1.h * W01 + a2.h * W10 + a3.h * W11;                 \
      A.u.fld = r.u; }
    BILC(x, x) BILC(y, y) BILC(z, z) BILC(w, w)
#undef BILC

    acc0 = __builtin_amdgcn_mfma_f32_16x16x32_f16(A.v, bq[j & 1][0], acc0, 0,0,0);
    acc1 = __builtin_amdgcn_mfma_f32_16x16x32_f16(A.v, bq[j & 1][1], acc1, 0,0,0);
    acc2 = __builtin_amdgcn_mfma_f32_16x16x32_f16(A.v, bq[j & 1][2], acc2, 0,0,0);
    acc3 = __builtin_amdgcn_mfma_f32_16x16x32_f16(A.v, bq[j & 1][3], acc3, 0,0,0);
  }

  __syncthreads();
  float* red = (float*)tile;
  if (gsel == 1) {
    *(f32x4*)&red[((pg * 4 + 0) * 64 + lane) * 4] = acc0;
    *(f32x4*)&red[((pg * 4 + 1) * 64 + lane) * 4] = acc1;
  } else {
    *(f32x4*)&red[((pg * 4 + 2) * 64 + lane) * 4] = acc2;
    *(f32x4*)&red[((pg * 4 + 3) * 64 + lane) * 4] = acc3;
  }
  __syncthreads();
  float* ob = out + pixin + kq * 4;
  if (gsel == 0) {
    acc0 += *(const f32x4*)&red[((pg * 4 + 0) * 64 + lane) * 4];
    acc1 += *(const f32x4*)&red[((pg * 4 + 1) * 64 + lane) * 4];
#pragma unroll
    for (int r = 0; r < 4; ++r) {
      ob[((b*64 +      colb) << 14) + r] = acc0[r];
      ob[((b*64 + 16 + colb) << 14) + r] = acc1[r];
    }
  } else {
    acc2 += *(const f32x4*)&red[((pg * 4 + 2) * 64 + lane) * 4];
    acc3 += *(const f32x4*)&red[((pg * 4 + 3) * 64 + lane) * 4];
#pragma unroll
    for (int r = 0; r < 4; ++r) {
      ob[((b*64 + 32 + colb) << 14) + r] = acc2[r];
      ob[((b*64 + 48 + colb) << 14) + r] = acc3[r];
    }
  }
}

// ================= ABLATION kernels (write to ws scratch) =================
// MODE 0: staging only. MODE 1: staging + phase-1 MFMA. MODE 2: staging +
// zero-offset phase 2 (all-LDS fast path, branch still evaluated).
// `zero` is a runtime 0: defeats cross-rep hoisting and constant folding.
template<int MODE, int REPS>
__global__ __launch_bounds__(1024, 4) void abl_kernel(const ushort* __restrict__ xt,
                                                      const ushort* __restrict__ pk_def,
                                                      const ushort* __restrict__ pk_off,
                                                      float* __restrict__ dump, int zero) {
  __shared__ ushort tile[8 * T_STRIDE];
  __shared__ _Float16 off_lds[8][36][18];
  const int t = threadIdx.x;
  const int lane = t & 63;
  const int wid = t >> 6;
  const int pg = wid >> 1, gsel = wid & 1;
  const int bid0 = blockIdx.x;
  int bid = (bid0 & 7) * 64 + (bid0 >> 3);
  const int b  = bid >> 7;
  const int ty = (bid >> 3) & 15;
  const int tx = bid & 7;
  const int y0t = ty * 8, x0t = tx * 16;
  const int TLY = max(0, y0t - 4), THY = min(127, y0t + 12);
  const int TLX = max(0, x0t - 4), THX = min(127, x0t + 20);
  const int Hd = THY - TLY + 1, Wd = THX - TLX + 1;

  const int h = y0t + pg;
  const int p = lane & 15, kq = lane >> 4;
  const int w_ = x0t + p;
  const int su = gsel * 4 + kq;
  const int colb = lane & 15;

  int pixoff[9]; bool tvalid[9];
#pragma unroll
  for (int kk = 0; kk < 9; ++kk) {
    int yk = h + kk / 3 - 1, xk = w_ + kk % 3 - 1;
    tvalid[kk] = ((unsigned)yk < 128u) && ((unsigned)xk < 128u);
    int yc = min(max(yk, 0), 127), xc = min(max(xk, 0), 127);
    pixoff[kk] = ((yc - TLY) * 25 + (xc - TLX)) * 8;
  }

  float sink = 0.f;
  f32x4 acc0={0,0,0,0}, acc1={0,0,0,0}, acc2={0,0,0,0}, acc3={0,0,0,0};

#pragma unroll 1
  for (int rep = 0; rep < REPS; ++rep) {
    { // staging (zero-dependent source index prevents cross-rep hoisting)
      const int xq = t & 31;
      const int r0 = t >> 5;
      const int nr = Hd * 8;
      for (int rr = r0; rr < nr; rr += 32) {
        const int yq = rr >> 3, seg = rr & 7;
        if (xq < Wd) {
          const ushort* src = xt + ((((b << 7) + TLY + yq) << 3) + seg) * 1024
                              + (TLX + xq) * 8 + (zero & rep) * 8;
          *(uint4*)&tile[seg * T_STRIDE + (yq * 25 + xq) * 8] = *(const uint4*)src;
        }
      }
    }
    __syncthreads();

    if constexpr (MODE == 0) {
      sink += (float)tile[(t * 13) % (8 * T_STRIDE)];
    }

    if constexpr (MODE == 1) {
      f32x4 oa0 = {0,0,0,0}, oa1 = {0,0,0,0}, oa2 = {0,0,0,0};
      const f16x8* pBo = (const f16x8*)pk_off;
      const int lz = lane + (zero & rep);  // defeat B-load hoisting
      f16x8 bo[2][2];
      if (gsel == 0) bo[0][0] = pBo[0*64 + lz];
      else { bo[0][0] = pBo[1*64 + lz]; bo[0][1] = pBo[2*64 + lz]; }
#pragma unroll
      for (int s = 0; s < 18; ++s) {
        if (s + 1 < 18) {
          if (gsel == 0) bo[(s + 1) & 1][0] = pBo[((s + 1)*3 + 0)*64 + lz];
          else { bo[(s + 1) & 1][0] = pBo[((s + 1)*3 + 1)*64 + lz];
                 bo[(s + 1) & 1][1] = pBo[((s + 1)*3 + 2)*64 + lz]; }
        }
        const int k = s >> 1, chalf = s & 1;
        uint4 t_ = *(const uint4*)&tile[(chalf * 4 + kq) * T_STRIDE + pixoff[k]];
        if (!tvalid[k]) { t_.x = 0; t_.y = 0; t_.z = 0; t_.w = 0; }
        union { uint4 u; f16x8 v; } A; A.u = t_;
        if (gsel == 0) {
          oa0 = __builtin_amdgcn_mfma_f32_16x16x32_f16(A.v, bo[s & 1][0], oa0, 0,0,0);
        } else {
          oa1 = __builtin_amdgcn_mfma_f32_16x16x32_f16(A.v, bo[s & 1][0], oa1, 0,0,0);
          oa2 = __builtin_amdgcn_mfma_f32_16x16x32_f16(A.v, bo[s & 1][1], oa2, 0,0,0);
        }
      }
      if (gsel == 0) {
#pragma unroll
        for (int r = 0; r < 4; ++r) off_lds[pg][colb][kq * 4 + r] = (_Float16)oa0[r];
      } else {
#pragma unroll
        for (int r = 0; r < 4; ++r) {
          off_lds[pg][16 + colb][kq * 4 + r] = (_Float16)oa1[r];
          if (colb < 4) off_lds[pg][32 + colb][kq * 4 + r] = (_Float16)oa2[r];
        }
      }
      __syncthreads();
      sink += (float)off_lds[pg][colb][p];
    }

    if constexpr (MODE == 2) {
      const float z = (float)zero;       // runtime 0.0: no constant folding
      const f16x8* pB = (const f16x8*)pk_def;
      f16x8 bq[2][4];
      {
        const int s0 = gsel * 9;
#pragma unroll
        for (int q = 0; q < 4; ++q) bq[0][q] = pB[(s0*4 + q)*64 + lane + (zero & rep)];
      }
#pragma unroll
      for (int j = 0; j < 9; ++j) {
        if (j + 1 < 9) {
          const int s1 = gsel * 9 + j + 1;
#pragma unroll
          for (int q = 0; q < 4; ++q) bq[(j + 1) & 1][q] = pB[(s1*4 + q)*64 + lane + (zero & rep)];
        }
        const int k = j;
        float py = z + (float)(h  + k / 3 - 1);
        float px = z + (float)(w_ + k % 3 - 1);
        float fy = floorf(py), fx = floorf(px);
        int y0 = (int)fy, x0 = (int)fx;
        float dy = py - fy, dx = px - fx;
        bool vy0 = (y0 >= 0) && (y0 < Hn);
        bool vy1 = (y0 >= -1) && (y0 < Hn - 1);
        bool vx0 = (x0 >= 0) && (x0 < Wn);
        bool vx1 = (x0 >= -1) && (x0 < Wn - 1);
        float omdy = 1.f - dy, omdx = 1.f - dx;
        float w00 = (vy0 && vx0) ? omdy * omdx : 0.f;
        float w01 = (vy0 && vx1) ? omdy * dx   : 0.f;
        float w10 = (vy1 && vx0) ? dy * omdx   : 0.f;
        float w11 = (vy1 && vx1) ? dy * dx     : 0.f;
        int iy0 = min(max(y0, 0), Hn - 1), iy1 = min(max(y0 + 1, 0), Hn - 1);
        int ix0 = min(max(x0, 0), Wn - 1), ix1 = min(max(x0 + 1, 0), Wn - 1);
        uint4 c00, c01, c10, c11;
        bool intile = (iy0 >= TLY) && (iy1 <= THY) && (ix0 >= TLX) && (ix1 <= THX);
        if (__all((int)intile)) {
          const int base = su * T_STRIDE;
          const int ly0 = iy0 - TLY, ly1 = iy1 - TLY;
          const int lx0 = ix0 - TLX, lx1 = ix1 - TLX;
          c00 = *(const uint4*)&tile[base + (ly0 * 25 + lx0) * 8];
          c01 = *(const uint4*)&tile[base + (ly0 * 25 + lx1) * 8];
          c10 = *(const uint4*)&tile[base + (ly1 * 25 + lx0) * 8];
          c11 = *(const uint4*)&tile[base + (ly1 * 25 + lx1) * 8];
        } else {
          const int r0g = ((((b << 7) + iy0) << 3) + su) * 128;
          const int r1g = ((((b << 7) + iy1) << 3) + su) * 128;
          c00 = *(const uint4*)(xt + (r0g + ix0) * 8);
          c01 = *(const uint4*)(xt + (r0g + ix1) * 8);
          c10 = *(const uint4*)(xt + (r1g + ix0) * 8);
          c11 = *(const uint4*)(xt + (r1g + ix1) * 8);
        }
        const _Float16 h00 = (_Float16)w00, h01 = (_Float16)w01;
        const _Float16 h10 = (_Float16)w10, h11 = (_Float16)w11;
        const f16x2 W00 = {h00, h00}, W01 = {h01, h01};
        const f16x2 W10 = {h10, h10}, W11 = {h11, h11};
        union U32H { unsigned u; f16x2 h; };
        union { uint4 u; f16x8 v; } A;
#define BILC(comp, fld)                                                        \
        { U32H a0, a1, a2, a3, r;                                              \
          a0.u = c00.comp; a1.u = c01.comp; a2.u = c10.comp; a3.u = c11.comp;  \
          r.h = a0.h * W00 + a1.h * W01 + a2.h * W10 + a3.h * W11;             \
          A.u.fld = r.u; }
        BILC(x, x) BILC(y, y) BILC(z, z) BILC(w, w)
#undef BILC
        acc0 = __builtin_amdgcn_mfma_f32_16x16x32_f16(A.v, bq[j & 1][0], acc0, 0,0,0);
        acc1 = __builtin_amdgcn_mfma_f32_16x16x32_f16(A.v, bq[j & 1][1], acc1, 0,0,0);
        acc2 = __builtin_amdgcn_mfma_f32_16x16x32_f16(A.v, bq[j & 1][2], acc2, 0,0,0);
        acc3 = __builtin_amdgcn_mfma_f32_16x16x32_f16(A.v, bq[j & 1][3], acc3, 0,0,0);
      }
    }
    __syncthreads();                     // tile reused next rep
  }

  sink += acc0[0] + acc1[1] + acc2[2] + acc3[3];
  dump[bid0 * 1024 + t] = sink;          // keep all work live
}

extern "C" void kernel_launch(void* const* d_in, const int* in_sizes, int n_in,
                              void* d_out, int out_size, void* d_ws, size_t ws_size,
                              hipStream_t stream) {
  const float* x     = (const float*)d_in[0];
  const float* w_off = (const float*)d_in[1];
  const float* w_def = (const float*)d_in[2];
  float* out = (float*)d_out;

  char* ws = (char*)d_ws;
  ushort* xt     = (ushort*)ws;
  ushort* pk_def = (ushort*)(ws + XT_BYTES);
  ushort* pk_off = (ushort*)(ws + XT_BYTES + PKDEF_BYTES);
  float*  dump   = (float*)(ws + DUMP_OFF);

  prep_all<<<1056, 256, 0, stream>>>(x, w_off, w_def, xt, pk_def, pk_off);
  abl_kernel<0, 24><<<512, 1024, 0, stream>>>(xt, pk_def, pk_off, dump, 0);
  abl_kernel<1, 6><<<512, 1024, 0, stream>>>(xt, pk_def, pk_off, dump, 0);
  abl_kernel<2, 4><<<512, 1024, 0, stream>>>(xt, pk_def, pk_off, dump, 0);
  deform_fused<<<512, 1024, 0, stream>>>(xt, pk_def, pk_off, out);
}

// Round 15
// 58.216 us; speedup vs baseline: 6.1882x; 6.1882x over previous
//
#include <hip/hip_runtime.h>
#include <hip/hip_bf16.h>

typedef _Float16 f16x8 __attribute__((ext_vector_type(8)));
typedef _Float16 f16x2 __attribute__((ext_vector_type(2)));
typedef float f32x4  __attribute__((ext_vector_type(4)));

#define Bn 4
#define Cn 64
#define Hn 128
#define Wn 128
#define HWn 16384

#define XT_BYTES    (Bn*HWn*Cn*2)
#define PKDEF_BYTES (18*4*64*8*2)

// tile seg-plane: 17 rows x 25 cols x 8ch, FULLY LINEAR (no pad: R10 showed
// the pad was useless, and linearity is required for global_load_lds dest).
#define T_STRIDE (17*25*8)        // 3400 ushorts per seg-plane
#define TILE_USH (8*T_STRIDE)     // 27,200 ushorts = 54,400 B per tile

static __device__ __forceinline__ unsigned pk_f16(float lo, float hi) {
  union { _Float16 h[2]; unsigned u; } cv;
  cv.h[0] = (_Float16)lo; cv.h[1] = (_Float16)hi;
  return cv.u;
}

static __device__ __forceinline__ void gload16(const ushort* g, ushort* l) {
  __builtin_amdgcn_global_load_lds(
      (const __attribute__((address_space(1))) void*)g,
      (__attribute__((address_space(3))) void*)l, 16, 0, 0);
}

// ---- merged: blocks 0..1023 transpose x -> xt; blocks 1024..1055 pack weights.
__global__ __launch_bounds__(256) void prep_all(const float* __restrict__ x,
                                                const float* __restrict__ w_off,
                                                const float* __restrict__ w_def,
                                                ushort* __restrict__ xt,
                                                ushort* __restrict__ pk_def,
                                                ushort* __restrict__ pk_off) {
  __shared__ float tile[64][68];
  const int t = threadIdx.x;
  const int blk = blockIdx.x;
  if (blk < 1024) {
    const int b = blk >> 8;
    const int pix0 = (blk & 255) * 64;
    const int y = pix0 >> 7, x0 = pix0 & 127;
    const float* xb = x + (b * Cn) * HWn + pix0;
#pragma unroll
    for (int q = 0; q < 4; ++q) {
      int idx = q * 256 + t;
      int c = idx >> 4, p4 = idx & 15;
      float4 v = *(const float4*)(xb + c * HWn + p4 * 4);
      *(float4*)&tile[c][p4 * 4] = v;
    }
    __syncthreads();
    const int p = t & 63, cg = t >> 6;
#pragma unroll
    for (int half = 0; half < 2; ++half) {
      const int seg = cg * 2 + half;
      unsigned u[4];
#pragma unroll
      for (int j = 0; j < 4; ++j)
        u[j] = pk_f16(tile[seg * 8 + 2 * j][p], tile[seg * 8 + 2 * j + 1][p]);
      uint4 v = {u[0], u[1], u[2], u[3]};
      *(uint4*)(xt + (((((b << 7) + y) << 3) + seg) * 128 + x0 + p) * 8) = v;
    }
  } else {
    const int tt = (blk - 1024) * 256 + t;
    if (tt < 4608) {
      int lane = tt & 63, oc = (tt >> 6) & 3, s = tt >> 8;
      int g = s / 9, k = s % 9;
      int o = oc * 16 + (lane & 15);
      int cb = g * 32 + (lane >> 4) * 8;
      unsigned u[4];
#pragma unroll
      for (int j = 0; j < 4; ++j)
        u[j] = pk_f16(w_def[(o * Cn + cb + 2 * j) * 9 + k],
                      w_def[(o * Cn + cb + 2 * j + 1) * 9 + k]);
      uint4 v = {u[0], u[1], u[2], u[3]};
      *(uint4*)(pk_def + tt * 8) = v;
    } else if (tt < 8064) {
      int t2 = tt - 4608;
      int lane = t2 & 63, r = t2 >> 6;
      int oc = r % 3, s = r / 3;
      int k = s >> 1, chalf = s & 1;
      int o = oc * 16 + (lane & 15);
      int cb = chalf * 32 + (lane >> 4) * 8;
      unsigned u[4];
#pragma unroll
      for (int j = 0; j < 4; ++j) {
        float lo = (o < 36) ? w_off[(o * Cn + cb + 2 * j) * 9 + k] : 0.f;
        float hi = (o < 36) ? w_off[(o * Cn + cb + 2 * j + 1) * 9 + k] : 0.f;
        u[j] = pk_f16(lo, hi);
      }
      uint4 v = {u[0], u[1], u[2], u[3]};
      *(uint4*)(pk_off + (r * 64 + lane) * 8) = v;
    }
  }
}

// ---- FUSED, 2 tiles/block with cross-tile staging overlap.
// Grid 256 = 1 block/CU. Block = 1024 thr = 16 waves = 8 pg x 2 gsel.
// LDS: 2 x 54,400 (tiles) + 10,368 (off_lds) = 119,168 B.
__global__ __launch_bounds__(1024, 4) void deform_fused(const ushort* __restrict__ xt,
                                                        const ushort* __restrict__ pk_def,
                                                        const ushort* __restrict__ pk_off,
                                                        float* __restrict__ out) {
  __shared__ __align__(16) ushort tA[TILE_USH];
  __shared__ __align__(16) ushort tB[TILE_USH];
  __shared__ _Float16 off_lds[8][36][18];
  const int t = threadIdx.x;
  const int lane = t & 63;
  const int wid = t >> 6;                // 0..15
  const int pg = wid >> 1, gsel = wid & 1;
  int bid = blockIdx.x;
  bid = (bid & 7) * 32 + (bid >> 3);     // bijective XCD swizzle (256 % 8 == 0)
  const int b   = bid >> 6;
  const int typ = (bid >> 3) & 7;        // tile-pair row
  const int tx  = bid & 7;
  const int x0t = tx * 16;

  const int p = lane & 15, kq = lane >> 4;
  const int w_ = x0t + p;
  const int su = gsel * 4 + kq;
  const int colb = lane & 15;
  const f16x8* pB  = (const f16x8*)pk_def;
  const f16x8* pBo = (const f16x8*)pk_off;

  // ---- stage: issue 3400 async 16B global->LDS loads, linear LDS dest.
  auto stage = [&](ushort* tbuf, int y0t) {
    const int TLY = max(0, y0t - 4);
    const int TLX = max(0, x0t - 4);
    for (int base = wid * 64; base < 3400; base += 1024) {
      int fi = base + lane;
      if (fi < 3400) {
        int seg = fi / 425;
        int r   = fi - seg * 425;
        int yq  = r / 25;
        int xq  = r - yq * 25;
        int gy = min(TLY + yq, 127);     // clamped dup rows/cols: unread garbage
        int gx = min(TLX + xq, 127);
        const ushort* src = xt + ((((b << 7) + gy) << 3) + seg) * 1024 + gx * 8;
        gload16(src, tbuf + base * 8);   // wave-uniform base; HW adds lane*16
      }
    }
  };

  // ---- phase 1: offset conv -> off_lds
  auto P1 = [&](const ushort* tbuf, int y0t) {
    const int TLY = max(0, y0t - 4);
    const int TLX = max(0, x0t - 4);
    const int h = y0t + pg;
    int pixoff[9]; bool tvalid[9];
#pragma unroll
    for (int kk = 0; kk < 9; ++kk) {
      int yk = h + kk / 3 - 1, xk = w_ + kk % 3 - 1;
      tvalid[kk] = ((unsigned)yk < 128u) && ((unsigned)xk < 128u);
      int yc = min(max(yk, 0), 127), xc = min(max(xk, 0), 127);
      pixoff[kk] = ((yc - TLY) * 25 + (xc - TLX)) * 8;
    }
    f32x4 oa0 = {0,0,0,0}, oa1 = {0,0,0,0}, oa2 = {0,0,0,0};
    f16x8 bo[2][2];
    if (gsel == 0) bo[0][0] = pBo[0*64 + lane];
    else { bo[0][0] = pBo[1*64 + lane]; bo[0][1] = pBo[2*64 + lane]; }
#pragma unroll
    for (int s = 0; s < 18; ++s) {
      if (s + 1 < 18) {
        if (gsel == 0) bo[(s + 1) & 1][0] = pBo[((s + 1)*3 + 0)*64 + lane];
        else { bo[(s + 1) & 1][0] = pBo[((s + 1)*3 + 1)*64 + lane];
               bo[(s + 1) & 1][1] = pBo[((s + 1)*3 + 2)*64 + lane]; }
      }
      const int k = s >> 1, chalf = s & 1;
      uint4 t_ = *(const uint4*)&tbuf[(chalf * 4 + kq) * T_STRIDE + pixoff[k]];
      if (!tvalid[k]) { t_.x = 0; t_.y = 0; t_.z = 0; t_.w = 0; }
      union { uint4 u; f16x8 v; } A; A.u = t_;
      if (gsel == 0) {
        oa0 = __builtin_amdgcn_mfma_f32_16x16x32_f16(A.v, bo[s & 1][0], oa0, 0,0,0);
      } else {
        oa1 = __builtin_amdgcn_mfma_f32_16x16x32_f16(A.v, bo[s & 1][0], oa1, 0,0,0);
        oa2 = __builtin_amdgcn_mfma_f32_16x16x32_f16(A.v, bo[s & 1][1], oa2, 0,0,0);
      }
    }
    if (gsel == 0) {
#pragma unroll
      for (int r = 0; r < 4; ++r) off_lds[pg][colb][kq * 4 + r] = (_Float16)oa0[r];
    } else {
#pragma unroll
      for (int r = 0; r < 4; ++r) {
        off_lds[pg][16 + colb][kq * 4 + r] = (_Float16)oa1[r];
        if (colb < 4) off_lds[pg][32 + colb][kq * 4 + r] = (_Float16)oa2[r];
      }
    }
  };

  f32x4 acc0, acc1, acc2, acc3;

  // ---- phase 2: deformable gather + packed-f16 bilinear + MFMA
  auto P2 = [&](const ushort* tbuf, int y0t) {
    const int TLY = max(0, y0t - 4), THY = min(127, y0t + 12);
    const int TLX = max(0, x0t - 4), THX = min(127, x0t + 20);
    const int h = y0t + pg;
    float offv[18];
#pragma unroll
    for (int j = 0; j < 18; ++j) offv[j] = (float)off_lds[pg][gsel * 18 + j][p];
    acc0 = (f32x4){0,0,0,0}; acc1 = (f32x4){0,0,0,0};
    acc2 = (f32x4){0,0,0,0}; acc3 = (f32x4){0,0,0,0};
    f16x8 bq[2][4];
    {
      const int s0 = gsel * 9;
#pragma unroll
      for (int q = 0; q < 4; ++q) bq[0][q] = pB[(s0*4 + q)*64 + lane];
    }
#pragma unroll
    for (int j = 0; j < 9; ++j) {
      if (j + 1 < 9) {
        const int s1 = gsel * 9 + j + 1;
#pragma unroll
        for (int q = 0; q < 4; ++q) bq[(j + 1) & 1][q] = pB[(s1*4 + q)*64 + lane];
      }
      const int k = j;
      float py = offv[2*j]   + (float)(h  + k / 3 - 1);
      float px = offv[2*j+1] + (float)(w_ + k % 3 - 1);
      float fy = floorf(py), fx = floorf(px);
      int y0 = (int)fy, x0 = (int)fx;
      float dy = py - fy, dx = px - fx;
      bool vy0 = (y0 >= 0) && (y0 < Hn);
      bool vy1 = (y0 >= -1) && (y0 < Hn - 1);
      bool vx0 = (x0 >= 0) && (x0 < Wn);
      bool vx1 = (x0 >= -1) && (x0 < Wn - 1);
      float omdy = 1.f - dy, omdx = 1.f - dx;
      float w00 = (vy0 && vx0) ? omdy * omdx : 0.f;
      float w01 = (vy0 && vx1) ? omdy * dx   : 0.f;
      float w10 = (vy1 && vx0) ? dy * omdx   : 0.f;
      float w11 = (vy1 && vx1) ? dy * dx     : 0.f;
      int iy0 = min(max(y0, 0), Hn - 1), iy1 = min(max(y0 + 1, 0), Hn - 1);
      int ix0 = min(max(x0, 0), Wn - 1), ix1 = min(max(x0 + 1, 0), Wn - 1);
      uint4 c00, c01, c10, c11;
      bool intile = (iy0 >= TLY) && (iy1 <= THY) && (ix0 >= TLX) && (ix1 <= THX);
      if (__all((int)intile)) {          // fast path: LDS
        const int base = su * T_STRIDE;
        const int ly0 = iy0 - TLY, ly1 = iy1 - TLY;
        const int lx0 = ix0 - TLX, lx1 = ix1 - TLX;
        c00 = *(const uint4*)&tbuf[base + (ly0 * 25 + lx0) * 8];
        c01 = *(const uint4*)&tbuf[base + (ly0 * 25 + lx1) * 8];
        c10 = *(const uint4*)&tbuf[base + (ly1 * 25 + lx0) * 8];
        c11 = *(const uint4*)&tbuf[base + (ly1 * 25 + lx1) * 8];
      } else {                           // rare fallback: global gather
        const int r0g = ((((b << 7) + iy0) << 3) + su) * 128;
        const int r1g = ((((b << 7) + iy1) << 3) + su) * 128;
        c00 = *(const uint4*)(xt + (r0g + ix0) * 8);
        c01 = *(const uint4*)(xt + (r0g + ix1) * 8);
        c10 = *(const uint4*)(xt + (r1g + ix0) * 8);
        c11 = *(const uint4*)(xt + (r1g + ix1) * 8);
      }
      const _Float16 h00 = (_Float16)w00, h01 = (_Float16)w01;
      const _Float16 h10 = (_Float16)w10, h11 = (_Float16)w11;
      const f16x2 W00 = {h00, h00}, W01 = {h01, h01};
      const f16x2 W10 = {h10, h10}, W11 = {h11, h11};
      union U32H { unsigned u; f16x2 h; };
      union { uint4 u; f16x8 v; } A;
#define BILC(comp, fld)                                                        \
      { U32H a0, a1, a2, a3, r;                                                \
        a0.u = c00.comp; a1.u = c01.comp; a2.u = c10.comp; a3.u = c11.comp;    \
        r.h = a0.h * W00 + a1.h * W01 + a2.h * W10 + a3.h * W11;               \
        A.u.fld = r.u; }
      BILC(x, x) BILC(y, y) BILC(z, z) BILC(w, w)
#undef BILC
      acc0 = __builtin_amdgcn_mfma_f32_16x16x32_f16(A.v, bq[j & 1][0], acc0, 0,0,0);
      acc1 = __builtin_amdgcn_mfma_f32_16x16x32_f16(A.v, bq[j & 1][1], acc1, 0,0,0);
      acc2 = __builtin_amdgcn_mfma_f32_16x16x32_f16(A.v, bq[j & 1][2], acc2, 0,0,0);
      acc3 = __builtin_amdgcn_mfma_f32_16x16x32_f16(A.v, bq[j & 1][3], acc3, 0,0,0);
    }
  };

  // ---- reduce + write (red aliases the given tile region)
  auto RW = [&](float* red, int y0t) {
    const int h = y0t + pg;
    const int pixin = (h << 7) + x0t;
    if (gsel == 1) {
      *(f32x4*)&red[((pg * 4 + 0) * 64 + lane) * 4] = acc0;
      *(f32x4*)&red[((pg * 4 + 1) * 64 + lane) * 4] = acc1;
    } else {
      *(f32x4*)&red[((pg * 4 + 2) * 64 + lane) * 4] = acc2;
      *(f32x4*)&red[((pg * 4 + 3) * 64 + lane) * 4] = acc3;
    }
    __syncthreads();
    float* ob = out + pixin + kq * 4;
    if (gsel == 0) {
      acc0 += *(const f32x4*)&red[((pg * 4 + 0) * 64 + lane) * 4];
      acc1 += *(const f32x4*)&red[((pg * 4 + 1) * 64 + lane) * 4];
#pragma unroll
      for (int r = 0; r < 4; ++r) {
        ob[((b*64 +      colb) << 14) + r] = acc0[r];
        ob[((b*64 + 16 + colb) << 14) + r] = acc1[r];
      }
    } else {
      acc2 += *(const f32x4*)&red[((pg * 4 + 2) * 64 + lane) * 4];
      acc3 += *(const f32x4*)&red[((pg * 4 + 3) * 64 + lane) * 4];
#pragma unroll
      for (int r = 0; r < 4; ++r) {
        ob[((b*64 + 32 + colb) << 14) + r] = acc2[r];
        ob[((b*64 + 48 + colb) << 14) + r] = acc3[r];
      }
    }
  };

  const int y0t0 = typ * 16;             // tile 0: rows [typ*16,   typ*16+8)
  const int y0t1 = typ * 16 + 8;         // tile 1: rows [typ*16+8, typ*16+16)

  // ---- pipelined schedule
  stage(tA, y0t0);
  __syncthreads();                       // vmcnt(0) at barrier: A ready
  P1(tA, y0t0);
  __syncthreads();                       // off_lds ready
  stage(tB, y0t1);                       // PREFETCH: in flight under P2(A)
  P2(tA, y0t0);
  __syncthreads();                       // drains B's loads (long complete)
  RW((float*)tA, y0t0);
  __syncthreads();                       // off_lds + red free; B ready
  P1(tB, y0t1);
  __syncthreads();
  P2(tB, y0t1);
  __syncthreads();
  RW((float*)tB, y0t1);
}

extern "C" void kernel_launch(void* const* d_in, const int* in_sizes, int n_in,
                              void* d_out, int out_size, void* d_ws, size_t ws_size,
                              hipStream_t stream) {
  const float* x     = (const float*)d_in[0];
  const float* w_off = (const float*)d_in[1];
  const float* w_def = (const float*)d_in[2];
  float* out = (float*)d_out;

  char* ws = (char*)d_ws;
  ushort* xt     = (ushort*)ws;
  ushort* pk_def = (ushort*)(ws + XT_BYTES);
  ushort* pk_off = (ushort*)(ws + XT_BYTES + PKDEF_BYTES);

  prep_all<<<1056, 256, 0, stream>>>(x, w_off, w_def, xt, pk_def, pk_off);
  deform_fused<<<256, 1024, 0, stream>>>(xt, pk_def, pk_off, out);
}

// Round 16
// 47.181 us; speedup vs baseline: 7.6355x; 1.2339x over previous
//
#include <hip/hip_runtime.h>
#include <hip/hip_bf16.h>

typedef _Float16 f16x8 __attribute__((ext_vector_type(8)));
typedef _Float16 f16x2 __attribute__((ext_vector_type(2)));
typedef float f32x4  __attribute__((ext_vector_type(4)));

#define Bn 4
#define Cn 64
#define Hn 128
#define Wn 128
#define HWn 16384

// ws layout (bytes):
//   xt     [B][H][seg0..7][W][8ch] f16 @ 0   (8 MB)
//   pk_def [18][4][64][8] f16 @ XT_BYTES     B-frags, main conv
//   pk_off [18][3][64][8] f16 @ +PKDEF       B-frags, offset conv
#define XT_BYTES    (Bn*HWn*Cn*2)
#define PKDEF_BYTES (18*4*64*8*2)

static __device__ __forceinline__ unsigned pk_f16(float lo, float hi) {
  union { _Float16 h[2]; unsigned u; } cv;
  cv.h[0] = (_Float16)lo; cv.h[1] = (_Float16)hi;
  return cv.u;
}

// ---- merged: blocks 0..1023 transpose x -> xt (float4 loads); 1024..1055 pack.
__global__ __launch_bounds__(256) void prep_all(const float* __restrict__ x,
                                                const float* __restrict__ w_off,
                                                const float* __restrict__ w_def,
                                                ushort* __restrict__ xt,
                                                ushort* __restrict__ pk_def,
                                                ushort* __restrict__ pk_off) {
  __shared__ float tile[64][68];         // stride 68 f32: 16B-aligned rows
  const int t = threadIdx.x;
  const int blk = blockIdx.x;
  if (blk < 1024) {                      // ---- transpose_cast
    const int b = blk >> 8;
    const int pix0 = (blk & 255) * 64;
    const int y = pix0 >> 7, x0 = pix0 & 127;
    const float* xb = x + (b * Cn) * HWn + pix0;
#pragma unroll
    for (int q = 0; q < 4; ++q) {        // float4 loads: 16B/lane
      int idx = q * 256 + t;             // 1024 slots = 64 rows x 16 float4
      int c = idx >> 4, p4 = idx & 15;
      float4 v = *(const float4*)(xb + c * HWn + p4 * 4);
      *(float4*)&tile[c][p4 * 4] = v;
    }
    __syncthreads();
    const int p = t & 63, cg = t >> 6;
#pragma unroll
    for (int half = 0; half < 2; ++half) {
      const int seg = cg * 2 + half;
      unsigned u[4];
#pragma unroll
      for (int j = 0; j < 4; ++j)
        u[j] = pk_f16(tile[seg * 8 + 2 * j][p], tile[seg * 8 + 2 * j + 1][p]);
      uint4 v = {u[0], u[1], u[2], u[3]};
      *(uint4*)(xt + (((((b << 7) + y) << 3) + seg) * 128 + x0 + p) * 8) = v;
    }
  } else {                               // ---- prep_pack
    const int tt = (blk - 1024) * 256 + t;
    if (tt < 4608) {                     // 18*4*64
      int lane = tt & 63, oc = (tt >> 6) & 3, s = tt >> 8;
      int g = s / 9, k = s % 9;
      int o = oc * 16 + (lane & 15);
      int cb = g * 32 + (lane >> 4) * 8;
      unsigned u[4];
#pragma unroll
      for (int j = 0; j < 4; ++j)
        u[j] = pk_f16(w_def[(o * Cn + cb + 2 * j) * 9 + k],
                      w_def[(o * Cn + cb + 2 * j + 1) * 9 + k]);
      uint4 v = {u[0], u[1], u[2], u[3]};
      *(uint4*)(pk_def + tt * 8) = v;
    } else if (tt < 8064) {              // + 18*3*64
      int t2 = tt - 4608;
      int lane = t2 & 63, r = t2 >> 6;   // r = s*3 + oc
      int oc = r % 3, s = r / 3;
      int k = s >> 1, chalf = s & 1;
      int o = oc * 16 + (lane & 15);
      int cb = chalf * 32 + (lane >> 4) * 8;
      unsigned u[4];
#pragma unroll
      for (int j = 0; j < 4; ++j) {
        float lo = (o < 36) ? w_off[(o * Cn + cb + 2 * j) * 9 + k] : 0.f;
        float hi = (o < 36) ? w_off[(o * Cn + cb + 2 * j + 1) * 9 + k] : 0.f;
        u[j] = pk_f16(lo, hi);
      }
      uint4 v = {u[0], u[1], u[2], u[3]};
      *(uint4*)(pk_off + (r * 64 + lane) * 8) = v;
    }
  }
}

// ---- FUSED: round-10-bench structure (lb(1024,8), 2 blocks/CU, no setprio)
// with x-halo widened to +/-4: rows of 25. LDS 54,400 + 10,368 = 64,768 B.
#define T_STRIDE (17*25*8)
__global__ __launch_bounds__(1024, 8) void deform_fused(const ushort* __restrict__ xt,
                                                        const ushort* __restrict__ pk_def,
                                                        const ushort* __restrict__ pk_off,
                                                        float* __restrict__ out) {
  __shared__ ushort tile[8 * T_STRIDE];      // 54,400 B (reduce buf aliases later)
  __shared__ _Float16 off_lds[8][36][18];    // 10,368 B
  const int t = threadIdx.x;
  const int lane = t & 63;
  const int wid = t >> 6;                // 0..15
  const int pg = wid >> 1, gsel = wid & 1;
  int bid = blockIdx.x;
  bid = (bid & 7) * 64 + (bid >> 3);     // bijective XCD swizzle (512 % 8 == 0)
  const int b  = bid >> 7;
  const int ty = (bid >> 3) & 15;
  const int tx = bid & 7;
  const int y0t = ty * 8, x0t = tx * 16;
  const int TLY = max(0, y0t - 4), THY = min(127, y0t + 12);
  const int TLX = max(0, x0t - 4), THX = min(127, x0t + 20);
  const int Hd = THY - TLY + 1, Wd = THX - TLX + 1;

  { // stage [8 seg][Hd][Wd][8ch] -> LDS (coalesced 16B/lane)
    const int xq = t & 31;
    const int r0 = t >> 5;               // 32 row-groups
    const int nr = Hd * 8;
    for (int rr = r0; rr < nr; rr += 32) {
      const int yq = rr >> 3, seg = rr & 7;
      if (xq < Wd) {
        const ushort* src = xt + ((((b << 7) + TLY + yq) << 3) + seg) * 1024 + (TLX + xq) * 8;
        *(uint4*)&tile[seg * T_STRIDE + (yq * 25 + xq) * 8] = *(const uint4*)src;
      }
    }
  }
  __syncthreads();

  const int h = y0t + pg;
  const int p = lane & 15, kq = lane >> 4;
  const int w_ = x0t + p;
  const int pixin = (h << 7) + x0t;
  const int su = gsel * 4 + kq;
  const int colb = lane & 15;

  // hoisted per-tap data for the regular 3x3 (shared by ph1's two ch-halves)
  int pixoff[9]; bool tvalid[9];
#pragma unroll
  for (int kk = 0; kk < 9; ++kk) {
    int yk = h + kk / 3 - 1, xk = w_ + kk % 3 - 1;
    tvalid[kk] = ((unsigned)yk < 128u) && ((unsigned)xk < 128u);
    int yc = min(max(yk, 0), 127), xc = min(max(xk, 0), 127);
    pixoff[kk] = ((yc - TLY) * 25 + (xc - TLX)) * 8;
  }

  // ---- phase 1: offset conv from staged tile.
  // N-split: gsel0 -> off ch 0-15; gsel1 -> 16-31 & 32-35.
  {
    f32x4 oa0 = {0,0,0,0}, oa1 = {0,0,0,0}, oa2 = {0,0,0,0};
    const f16x8* pBo = (const f16x8*)pk_off;
#pragma unroll
    for (int s = 0; s < 18; ++s) {
      const int k = s >> 1, chalf = s & 1;
      uint4 t_ = *(const uint4*)&tile[(chalf * 4 + kq) * T_STRIDE + pixoff[k]];
      if (!tvalid[k]) { t_.x = 0; t_.y = 0; t_.z = 0; t_.w = 0; }
      union { uint4 u; f16x8 v; } A; A.u = t_;
      if (gsel == 0) {
        oa0 = __builtin_amdgcn_mfma_f32_16x16x32_f16(A.v, pBo[(s*3 + 0)*64 + lane], oa0, 0,0,0);
      } else {
        oa1 = __builtin_amdgcn_mfma_f32_16x16x32_f16(A.v, pBo[(s*3 + 1)*64 + lane], oa1, 0,0,0);
        oa2 = __builtin_amdgcn_mfma_f32_16x16x32_f16(A.v, pBo[(s*3 + 2)*64 + lane], oa2, 0,0,0);
      }
    }
    // D: col = lane&15 = offset channel (within 16-group), row = kq*4+r = pixel x
    if (gsel == 0) {
#pragma unroll
      for (int r = 0; r < 4; ++r) off_lds[pg][colb][kq * 4 + r] = (_Float16)oa0[r];
    } else {
#pragma unroll
      for (int r = 0; r < 4; ++r) {
        off_lds[pg][16 + colb][kq * 4 + r] = (_Float16)oa1[r];
        if (colb < 4) off_lds[pg][32 + colb][kq * 4 + r] = (_Float16)oa2[r];
      }
    }
  }
  __syncthreads();

  // this wave's 18 offset channels for its pixel (broadcast across kq)
  float offv[18];
#pragma unroll
  for (int j = 0; j < 18; ++j) offv[j] = (float)off_lds[pg][gsel * 18 + j][p];

  // ---- phase 2: deformable gather + packed-f16 bilinear + main MFMA
  f32x4 acc0={0,0,0,0}, acc1={0,0,0,0}, acc2={0,0,0,0}, acc3={0,0,0,0};
  const f16x8* pB = (const f16x8*)pk_def;

#pragma unroll
  for (int j = 0; j < 9; ++j) {
    const int k = j;
    float py = offv[2*j]   + (float)(h  + k / 3 - 1);
    float px = offv[2*j+1] + (float)(w_ + k % 3 - 1);
    float fy = floorf(py), fx = floorf(px);
    int y0 = (int)fy, x0 = (int)fx;
    float dy = py - fy, dx = px - fx;

    bool vy0 = (y0 >= 0) && (y0 < Hn);
    bool vy1 = (y0 >= -1) && (y0 < Hn - 1);
    bool vx0 = (x0 >= 0) && (x0 < Wn);
    bool vx1 = (x0 >= -1) && (x0 < Wn - 1);
    float omdy = 1.f - dy, omdx = 1.f - dx;
    float w00 = (vy0 && vx0) ? omdy * omdx : 0.f;
    float w01 = (vy0 && vx1) ? omdy * dx   : 0.f;
    float w10 = (vy1 && vx0) ? dy * omdx   : 0.f;
    float w11 = (vy1 && vx1) ? dy * dx     : 0.f;

    int iy0 = min(max(y0, 0), Hn - 1), iy1 = min(max(y0 + 1, 0), Hn - 1);
    int ix0 = min(max(x0, 0), Wn - 1), ix1 = min(max(x0 + 1, 0), Wn - 1);

    uint4 c00, c01, c10, c11;
    bool intile = (iy0 >= TLY) && (iy1 <= THY) && (ix0 >= TLX) && (ix1 <= THX);
    if (__all((int)intile)) {            // fast path: LDS (margin 4: ~94% of taps)
      const int base = su * T_STRIDE;
      const int ly0 = iy0 - TLY, ly1 = iy1 - TLY;
      const int lx0 = ix0 - TLX, lx1 = ix1 - TLX;
      c00 = *(const uint4*)&tile[base + (ly0 * 25 + lx0) * 8];
      c01 = *(const uint4*)&tile[base + (ly0 * 25 + lx1) * 8];
      c10 = *(const uint4*)&tile[base + (ly1 * 25 + lx0) * 8];
      c11 = *(const uint4*)&tile[base + (ly1 * 25 + lx1) * 8];
    } else {                             // rare fallback: global gather (L2-hot)
      const int r0g = ((((b << 7) + iy0) << 3) + su) * 128;
      const int r1g = ((((b << 7) + iy1) << 3) + su) * 128;
      c00 = *(const uint4*)(xt + (r0g + ix0) * 8);
      c01 = *(const uint4*)(xt + (r0g + ix1) * 8);
      c10 = *(const uint4*)(xt + (r1g + ix0) * 8);
      c11 = *(const uint4*)(xt + (r1g + ix1) * 8);
    }

    // packed-f16 bilinear: result words ARE the f16 MFMA A-fragment
    const _Float16 h00 = (_Float16)w00, h01 = (_Float16)w01;
    const _Float16 h10 = (_Float16)w10, h11 = (_Float16)w11;
    const f16x2 W00 = {h00, h00}, W01 = {h01, h01};
    const f16x2 W10 = {h10, h10}, W11 = {h11, h11};
    union U32H { unsigned u; f16x2 h; };
    union { uint4 u; f16x8 v; } A;
#define BILC(comp, fld)                                                        \
    { U32H a0, a1, a2, a3, r;                                                  \
      a0.u = c00.comp; a1.u = c01.comp; a2.u = c10.comp; a3.u = c11.comp;      \
      r.h = a0.h * W00 + a1.h * W01 + a2.h * W10 + a3.h * W11;                 \
      A.u.fld = r.u; }
    BILC(x, x) BILC(y, y) BILC(z, z) BILC(w, w)
#undef BILC

    const int s = gsel * 9 + j;
    acc0 = __builtin_amdgcn_mfma_f32_16x16x32_f16(A.v, pB[(s*4 + 0)*64 + lane], acc0, 0,0,0);
    acc1 = __builtin_amdgcn_mfma_f32_16x16x32_f16(A.v, pB[(s*4 + 1)*64 + lane], acc1, 0,0,0);
    acc2 = __builtin_amdgcn_mfma_f32_16x16x32_f16(A.v, pB[(s*4 + 2)*64 + lane], acc2, 0,0,0);
    acc3 = __builtin_amdgcn_mfma_f32_16x16x32_f16(A.v, pB[(s*4 + 3)*64 + lane], acc3, 0,0,0);
  }

  __syncthreads();                       // all waves done with tile
  float* red = (float*)tile;             // [8][4][64][4] f32 = 32 KB (aliases tile)
  if (gsel == 1) {
    *(f32x4*)&red[((pg * 4 + 0) * 64 + lane) * 4] = acc0;
    *(f32x4*)&red[((pg * 4 + 1) * 64 + lane) * 4] = acc1;
    *(f32x4*)&red[((pg * 4 + 2) * 64 + lane) * 4] = acc2;
    *(f32x4*)&red[((pg * 4 + 3) * 64 + lane) * 4] = acc3;
  }
  __syncthreads();
  if (gsel == 0) {
    acc0 += *(const f32x4*)&red[((pg * 4 + 0) * 64 + lane) * 4];
    acc1 += *(const f32x4*)&red[((pg * 4 + 1) * 64 + lane) * 4];
    acc2 += *(const f32x4*)&red[((pg * 4 + 2) * 64 + lane) * 4];
    acc3 += *(const f32x4*)&red[((pg * 4 + 3) * 64 + lane) * 4];
    float* ob = out + pixin + kq * 4;
#pragma unroll
    for (int r = 0; r < 4; ++r) {
      ob[((b*64 +      colb) << 14) + r] = acc0[r];
      ob[((b*64 + 16 + colb) << 14) + r] = acc1[r];
      ob[((b*64 + 32 + colb) << 14) + r] = acc2[r];
      ob[((b*64 + 48 + colb) << 14) + r] = acc3[r];
    }
  }
}

extern "C" void kernel_launch(void* const* d_in, const int* in_sizes, int n_in,
                              void* d_out, int out_size, void* d_ws, size_t ws_size,
                              hipStream_t stream) {
  const float* x     = (const float*)d_in[0];
  const float* w_off = (const float*)d_in[1];
  const float* w_def = (const float*)d_in[2];
  float* out = (float*)d_out;

  char* ws = (char*)d_ws;
  ushort* xt     = (ushort*)ws;
  ushort* pk_def = (ushort*)(ws + XT_BYTES);
  ushort* pk_off = (ushort*)(ws + XT_BYTES + PKDEF_BYTES);

  prep_all<<<1056, 256, 0, stream>>>(x, w_off, w_def, xt, pk_def, pk_off);
  deform_fused<<<512, 1024, 0, stream>>>(xt, pk_def, pk_off, out);
}

// Round 17
// 46.946 us; speedup vs baseline: 7.6738x; 1.0050x over previous
//
#include <hip/hip_runtime.h>
#include <hip/hip_bf16.h>

typedef _Float16 f16x8 __attribute__((ext_vector_type(8)));
typedef _Float16 f16x2 __attribute__((ext_vector_type(2)));
typedef float f32x4  __attribute__((ext_vector_type(4)));

#define Bn 4
#define Cn 64
#define Hn 128
#define Wn 128
#define HWn 16384

// ws layout (bytes):
//   xt     [B][H][seg0..7][W][8ch] f16 @ 0   (8 MB)
//   pk_def [18][4][64][8] f16 @ XT_BYTES     B-frags, main conv
//   pk_off [18][3][64][8] f16 @ +PKDEF       B-frags, offset conv
#define XT_BYTES    (Bn*HWn*Cn*2)
#define PKDEF_BYTES (18*4*64*8*2)

static __device__ __forceinline__ unsigned pk_f16(float lo, float hi) {
  union { _Float16 h[2]; unsigned u; } cv;
  cv.h[0] = (_Float16)lo; cv.h[1] = (_Float16)hi;
  return cv.u;
}

// ---- merged: blocks 0..1023 transpose x -> xt (float4 loads); 1024..1055 pack.
__global__ __launch_bounds__(256) void prep_all(const float* __restrict__ x,
                                                const float* __restrict__ w_off,
                                                const float* __restrict__ w_def,
                                                ushort* __restrict__ xt,
                                                ushort* __restrict__ pk_def,
                                                ushort* __restrict__ pk_off) {
  __shared__ float tile[64][68];         // stride 68 f32: 16B-aligned rows
  const int t = threadIdx.x;
  const int blk = blockIdx.x;
  if (blk < 1024) {                      // ---- transpose_cast
    const int b = blk >> 8;
    const int pix0 = (blk & 255) * 64;
    const int y = pix0 >> 7, x0 = pix0 & 127;
    const float* xb = x + (b * Cn) * HWn + pix0;
#pragma unroll
    for (int q = 0; q < 4; ++q) {        // float4 loads: 16B/lane
      int idx = q * 256 + t;             // 1024 slots = 64 rows x 16 float4
      int c = idx >> 4, p4 = idx & 15;
      float4 v = *(const float4*)(xb + c * HWn + p4 * 4);
      *(float4*)&tile[c][p4 * 4] = v;
    }
    __syncthreads();
    const int p = t & 63, cg = t >> 6;
#pragma unroll
    for (int half = 0; half < 2; ++half) {
      const int seg = cg * 2 + half;
      unsigned u[4];
#pragma unroll
      for (int j = 0; j < 4; ++j)
        u[j] = pk_f16(tile[seg * 8 + 2 * j][p], tile[seg * 8 + 2 * j + 1][p]);
      uint4 v = {u[0], u[1], u[2], u[3]};
      *(uint4*)(xt + (((((b << 7) + y) << 3) + seg) * 128 + x0 + p) * 8) = v;
    }
  } else {                               // ---- prep_pack
    const int tt = (blk - 1024) * 256 + t;
    if (tt < 4608) {                     // 18*4*64
      int lane = tt & 63, oc = (tt >> 6) & 3, s = tt >> 8;
      int g = s / 9, k = s % 9;
      int o = oc * 16 + (lane & 15);
      int cb = g * 32 + (lane >> 4) * 8;
      unsigned u[4];
#pragma unroll
      for (int j = 0; j < 4; ++j)
        u[j] = pk_f16(w_def[(o * Cn + cb + 2 * j) * 9 + k],
                      w_def[(o * Cn + cb + 2 * j + 1) * 9 + k]);
      uint4 v = {u[0], u[1], u[2], u[3]};
      *(uint4*)(pk_def + tt * 8) = v;
    } else if (tt < 8064) {              // + 18*3*64
      int t2 = tt - 4608;
      int lane = t2 & 63, r = t2 >> 6;   // r = s*3 + oc
      int oc = r % 3, s = r / 3;
      int k = s >> 1, chalf = s & 1;
      int o = oc * 16 + (lane & 15);
      int cb = chalf * 32 + (lane >> 4) * 8;
      unsigned u[4];
#pragma unroll
      for (int j = 0; j < 4; ++j) {
        float lo = (o < 36) ? w_off[(o * Cn + cb + 2 * j) * 9 + k] : 0.f;
        float hi = (o < 36) ? w_off[(o * Cn + cb + 2 * j + 1) * 9 + k] : 0.f;
        u[j] = pk_f16(lo, hi);
      }
      uint4 v = {u[0], u[1], u[2], u[3]};
      *(uint4*)(pk_off + (r * 64 + lane) * 8) = v;
    }
  }
}

// ---- FUSED (R16 best-known) + T14 async halo staging:
// core rows [y0t-1, y0t+8] staged before P1; the 7 halo rows (P2-only) are
// ISSUED to registers after the first barrier and WRITTEN to LDS after P1 —
// their HBM latency hides under P1's MFMA work.
#define T_STRIDE (17*25*8)
__global__ __launch_bounds__(1024, 8) void deform_fused(const ushort* __restrict__ xt,
                                                        const ushort* __restrict__ pk_def,
                                                        const ushort* __restrict__ pk_off,
                                                        float* __restrict__ out) {
  __shared__ ushort tile[8 * T_STRIDE];      // 54,400 B (reduce buf aliases later)
  __shared__ _Float16 off_lds[8][36][18];    // 10,368 B
  const int t = threadIdx.x;
  const int lane = t & 63;
  const int wid = t >> 6;                // 0..15
  const int pg = wid >> 1, gsel = wid & 1;
  int bid = blockIdx.x;
  bid = (bid & 7) * 64 + (bid >> 3);     // bijective XCD swizzle (512 % 8 == 0)
  const int b  = bid >> 7;
  const int ty = (bid >> 3) & 15;
  const int tx = bid & 7;
  const int y0t = ty * 8, x0t = tx * 16;
  const int TLY = max(0, y0t - 4), THY = min(127, y0t + 12);
  const int TLX = max(0, x0t - 4), THX = min(127, x0t + 20);
  const int Wd = THX - TLX + 1;
  const int CLO = max(0, y0t - 1), CHI = min(127, y0t + 8);  // P1's row range

  { // stage CORE rows [CLO..CHI] -> LDS (coalesced 16B/lane)
    const int xq = t & 31;
    const int r0 = t >> 5;               // 32 row-groups
    const int nrc = (CHI - CLO + 1) * 8;
    for (int rr = r0; rr < nrc; rr += 32) {
      const int yq = rr >> 3, seg = rr & 7;
      const int gy = CLO + yq;
      if (xq < Wd) {
        const ushort* src = xt + ((((b << 7) + gy) << 3) + seg) * 1024 + (TLX + xq) * 8;
        *(uint4*)&tile[seg * T_STRIDE + ((gy - TLY) * 25 + xq) * 8] = *(const uint4*)src;
      }
    }
  }
  __syncthreads();                       // core ready (vmcnt(0) here, BEFORE halo issue)

  // ---- T14: issue halo-row loads NOW (registers), write to LDS after P1.
  const int nlow = CLO - TLY, nhigh = THY - CHI;
  const int nhalo = (nlow + nhigh) * 8 * 25;   // <= 1400 items of (row, seg, xq)
  uint4 hu0, hu1; int hl0 = -1, hl1 = -1;
  {
    int fi = t;
    if (fi < nhalo) {
      int xq = fi % 25; int r = fi / 25; int seg = r & 7; int hr = r >> 3;
      int gy = (hr < nlow) ? (TLY + hr) : (CHI + 1 + hr - nlow);
      int gx = min(TLX + xq, 127);       // clamped dup cols: never read
      hu0 = *(const uint4*)(xt + ((((b << 7) + gy) << 3) + seg) * 1024 + gx * 8);
      hl0 = seg * T_STRIDE + ((gy - TLY) * 25 + xq) * 8;
    }
    fi = t + 1024;
    if (fi < nhalo) {
      int xq = fi % 25; int r = fi / 25; int seg = r & 7; int hr = r >> 3;
      int gy = (hr < nlow) ? (TLY + hr) : (CHI + 1 + hr - nlow);
      int gx = min(TLX + xq, 127);
      hu1 = *(const uint4*)(xt + ((((b << 7) + gy) << 3) + seg) * 1024 + gx * 8);
      hl1 = seg * T_STRIDE + ((gy - TLY) * 25 + xq) * 8;
    }
  }

  const int h = y0t + pg;
  const int p = lane & 15, kq = lane >> 4;
  const int w_ = x0t + p;
  const int pixin = (h << 7) + x0t;
  const int su = gsel * 4 + kq;
  const int colb = lane & 15;

  // hoisted per-tap data for the regular 3x3 (rows all within CORE)
  int pixoff[9]; bool tvalid[9];
#pragma unroll
  for (int kk = 0; kk < 9; ++kk) {
    int yk = h + kk / 3 - 1, xk = w_ + kk % 3 - 1;
    tvalid[kk] = ((unsigned)yk < 128u) && ((unsigned)xk < 128u);
    int yc = min(max(yk, 0), 127), xc = min(max(xk, 0), 127);
    pixoff[kk] = ((yc - TLY) * 25 + (xc - TLX)) * 8;
  }

  // ---- phase 1: offset conv from staged core rows.
  // N-split: gsel0 -> off ch 0-15; gsel1 -> 16-31 & 32-35.
  {
    f32x4 oa0 = {0,0,0,0}, oa1 = {0,0,0,0}, oa2 = {0,0,0,0};
    const f16x8* pBo = (const f16x8*)pk_off;
#pragma unroll
    for (int s = 0; s < 18; ++s) {
      const int k = s >> 1, chalf = s & 1;
      uint4 t_ = *(const uint4*)&tile[(chalf * 4 + kq) * T_STRIDE + pixoff[k]];
      if (!tvalid[k]) { t_.x = 0; t_.y = 0; t_.z = 0; t_.w = 0; }
      union { uint4 u; f16x8 v; } A; A.u = t_;
      if (gsel == 0) {
        oa0 = __builtin_amdgcn_mfma_f32_16x16x32_f16(A.v, pBo[(s*3 + 0)*64 + lane], oa0, 0,0,0);
      } else {
        oa1 = __builtin_amdgcn_mfma_f32_16x16x32_f16(A.v, pBo[(s*3 + 1)*64 + lane], oa1, 0,0,0);
        oa2 = __builtin_amdgcn_mfma_f32_16x16x32_f16(A.v, pBo[(s*3 + 2)*64 + lane], oa2, 0,0,0);
      }
    }
    // D: col = lane&15 = offset channel (within 16-group), row = kq*4+r = pixel x
    if (gsel == 0) {
#pragma unroll
      for (int r = 0; r < 4; ++r) off_lds[pg][colb][kq * 4 + r] = (_Float16)oa0[r];
    } else {
#pragma unroll
      for (int r = 0; r < 4; ++r) {
        off_lds[pg][16 + colb][kq * 4 + r] = (_Float16)oa1[r];
        if (colb < 4) off_lds[pg][32 + colb][kq * 4 + r] = (_Float16)oa2[r];
      }
    }
  }

  // write the halo rows (loads have been in flight under all of P1)
  if (hl0 >= 0) *(uint4*)&tile[hl0] = hu0;
  if (hl1 >= 0) *(uint4*)&tile[hl1] = hu1;
  __syncthreads();                       // off_lds + full tile ready

  // this wave's 18 offset channels for its pixel (broadcast across kq)
  float offv[18];
#pragma unroll
  for (int j = 0; j < 18; ++j) offv[j] = (float)off_lds[pg][gsel * 18 + j][p];

  // ---- phase 2: deformable gather + packed-f16 bilinear + main MFMA
  f32x4 acc0={0,0,0,0}, acc1={0,0,0,0}, acc2={0,0,0,0}, acc3={0,0,0,0};
  const f16x8* pB = (const f16x8*)pk_def;

#pragma unroll
  for (int j = 0; j < 9; ++j) {
    const int k = j;
    float py = offv[2*j]   + (float)(h  + k / 3 - 1);
    float px = offv[2*j+1] + (float)(w_ + k % 3 - 1);
    float fy = floorf(py), fx = floorf(px);
    int y0 = (int)fy, x0 = (int)fx;
    float dy = py - fy, dx = px - fx;

    bool vy0 = (y0 >= 0) && (y0 < Hn);
    bool vy1 = (y0 >= -1) && (y0 < Hn - 1);
    bool vx0 = (x0 >= 0) && (x0 < Wn);
    bool vx1 = (x0 >= -1) && (x0 < Wn - 1);
    float omdy = 1.f - dy, omdx = 1.f - dx;
    float w00 = (vy0 && vx0) ? omdy * omdx : 0.f;
    float w01 = (vy0 && vx1) ? omdy * dx   : 0.f;
    float w10 = (vy1 && vx0) ? dy * omdx   : 0.f;
    float w11 = (vy1 && vx1) ? dy * dx     : 0.f;

    int iy0 = min(max(y0, 0), Hn - 1), iy1 = min(max(y0 + 1, 0), Hn - 1);
    int ix0 = min(max(x0, 0), Wn - 1), ix1 = min(max(x0 + 1, 0), Wn - 1);

    uint4 c00, c01, c10, c11;
    bool intile = (iy0 >= TLY) && (iy1 <= THY) && (ix0 >= TLX) && (ix1 <= THX);
    if (__all((int)intile)) {            // fast path: LDS (margin 4: ~94% of taps)
      const int base = su * T_STRIDE;
      const int ly0 = iy0 - TLY, ly1 = iy1 - TLY;
      const int lx0 = ix0 - TLX, lx1 = ix1 - TLX;
      c00 = *(const uint4*)&tile[base + (ly0 * 25 + lx0) * 8];
      c01 = *(const uint4*)&tile[base + (ly0 * 25 + lx1) * 8];
      c10 = *(const uint4*)&tile[base + (ly1 * 25 + lx0) * 8];
      c11 = *(const uint4*)&tile[base + (ly1 * 25 + lx1) * 8];
    } else {                             // rare fallback: global gather (L2-hot)
      const int r0g = ((((b << 7) + iy0) << 3) + su) * 128;
      const int r1g = ((((b << 7) + iy1) << 3) + su) * 128;
      c00 = *(const uint4*)(xt + (r0g + ix0) * 8);
      c01 = *(const uint4*)(xt + (r0g + ix1) * 8);
      c10 = *(const uint4*)(xt + (r1g + ix0) * 8);
      c11 = *(const uint4*)(xt + (r1g + ix1) * 8);
    }

    // packed-f16 bilinear: result words ARE the f16 MFMA A-fragment
    const _Float16 h00 = (_Float16)w00, h01 = (_Float16)w01;
    const _Float16 h10 = (_Float16)w10, h11 = (_Float16)w11;
    const f16x2 W00 = {h00, h00}, W01 = {h01, h01};
    const f16x2 W10 = {h10, h10}, W11 = {h11, h11};
    union U32H { unsigned u; f16x2 h; };
    union { uint4 u; f16x8 v; } A;
#define BILC(comp, fld)                                                        \
    { U32H a0, a1, a2, a3, r;                                                  \
      a0.u = c00.comp; a1.u = c01.comp; a2.u = c10.comp; a3.u = c11.comp;      \
      r.h = a0.h * W00 + a1.h * W01 + a2.h * W10 + a3.h * W11;                 \
      A.u.fld = r.u; }
    BILC(x, x) BILC(y, y) BILC(z, z) BILC(w, w)
#undef BILC

    const int s = gsel * 9 + j;
    acc0 = __builtin_amdgcn_mfma_f32_16x16x32_f16(A.v, pB[(s*4 + 0)*64 + lane], acc0, 0,0,0);
    acc1 = __builtin_amdgcn_mfma_f32_16x16x32_f16(A.v, pB[(s*4 + 1)*64 + lane], acc1, 0,0,0);
    acc2 = __builtin_amdgcn_mfma_f32_16x16x32_f16(A.v, pB[(s*4 + 2)*64 + lane], acc2, 0,0,0);
    acc3 = __builtin_amdgcn_mfma_f32_16x16x32_f16(A.v, pB[(s*4 + 3)*64 + lane], acc3, 0,0,0);
  }

  __syncthreads();                       // all waves done with tile
  float* red = (float*)tile;             // [8][4][64][4] f32 = 32 KB (aliases tile)
  if (gsel == 1) {
    *(f32x4*)&red[((pg * 4 + 0) * 64 + lane) * 4] = acc0;
    *(f32x4*)&red[((pg * 4 + 1) * 64 + lane) * 4] = acc1;
    *(f32x4*)&red[((pg * 4 + 2) * 64 + lane) * 4] = acc2;
    *(f32x4*)&red[((pg * 4 + 3) * 64 + lane) * 4] = acc3;
  }
  __syncthreads();
  if (gsel == 0) {
    acc0 += *(const f32x4*)&red[((pg * 4 + 0) * 64 + lane) * 4];
    acc1 += *(const f32x4*)&red[((pg * 4 + 1) * 64 + lane) * 4];
    acc2 += *(const f32x4*)&red[((pg * 4 + 2) * 64 + lane) * 4];
    acc3 += *(const f32x4*)&red[((pg * 4 + 3) * 64 + lane) * 4];
    float* ob = out + pixin + kq * 4;
#pragma unroll
    for (int r = 0; r < 4; ++r) {
      ob[((b*64 +      colb) << 14) + r] = acc0[r];
      ob[((b*64 + 16 + colb) << 14) + r] = acc1[r];
      ob[((b*64 + 32 + colb) << 14) + r] = acc2[r];
      ob[((b*64 + 48 + colb) << 14) + r] = acc3[r];
    }
  }
}

extern "C" void kernel_launch(void* const* d_in, const int* in_sizes, int n_in,
                              void* d_out, int out_size, void* d_ws, size_t ws_size,
                              hipStream_t stream) {
  const float* x     = (const float*)d_in[0];
  const float* w_off = (const float*)d_in[1];
  const float* w_def = (const float*)d_in[2];
  float* out = (float*)d_out;

  char* ws = (char*)d_ws;
  ushort* xt     = (ushort*)ws;
  ushort* pk_def = (ushort*)(ws + XT_BYTES);
  ushort* pk_off = (ushort*)(ws + XT_BYTES + PKDEF_BYTES);

  prep_all<<<1056, 256, 0, stream>>>(x, w_off, w_def, xt, pk_def, pk_off);
  deform_fused<<<512, 1024, 0, stream>>>(xt, pk_def, pk_off, out);
}